// Round 2
// baseline (211.022 us; speedup 1.0000x reference)
//
#include <hip/hip_runtime.h>
#include <hip/hip_bf16.h>

#define B_N 4096
#define S_N 200
#define E_N 32

typedef float f32x4 __attribute__((ext_vector_type(4)));
typedef short s16x8 __attribute__((ext_vector_type(8)));

__global__ __launch_bounds__(256, 4) void attn_pool_kernel(
    const float* __restrict__ am,    // [B,S,E]
    const float* __restrict__ lastm, // [B,E]
    const float* __restrict__ avgm,  // [B,E]
    const float* __restrict__ W1,    // [E,E]
    const float* __restrict__ b1,    // [E]
    const float* __restrict__ W2,    // [E,E]
    const float* __restrict__ b2,    // [E]
    const float* __restrict__ W3,    // [E,E]
    const float* __restrict__ b3,    // [E]
    const float* __restrict__ W4,    // [E,1]
    float* __restrict__ out)         // [B,E]
{
    const int tid  = threadIdx.x;
    const int l    = tid & 63;
    const int wave = tid >> 6;
    const int b    = blockIdx.x * 4 + wave;

    const int lm = l & 15;   // row-slot r within tile / A-frag row
    const int lg = l >> 4;   // 0..3 : k-slice group
    const int fi = l & 31;

    // ---- base[f] = b1+b2+b3[f] + (last@W2)[f] + (avg@W3)[f], computed at lane f=fi ----
    float lastv  = lastm[b * E_N + fi];
    float avgv   = avgm [b * E_N + fi];
    float base_f = b1[fi] + b2[fi] + b3[fi];
#pragma unroll
    for (int e = 0; e < E_N; ++e) {
        float le = __shfl(lastv, e);   // const lane -> readlane broadcast
        float ae = __shfl(avgv,  e);
        base_f += le * W2[e * E_N + fi] + ae * W3[e * E_N + fi];
    }
    // This lane's D rows are f = 4*lg+j (d0) and f = 16+4*lg+j (d1)
    float baseA[4], baseB[4], w4A[4], w4B[4];
#pragma unroll
    for (int j = 0; j < 4; ++j) {
        baseA[j] = __shfl(base_f, 4 * lg + j);
        baseB[j] = __shfl(base_f, 16 + 4 * lg + j);
        w4A[j]   = W4[4 * lg + j];
        w4B[j]   = W4[16 + 4 * lg + j];
    }

    // ---- W1 as MFMA *A* operand: A[m=f][k=e], lane holds row lm, k = 8*lg+i ----
    s16x8 w1A, w1B;
#pragma unroll
    for (int i = 0; i < 8; i += 2) {
        int e = 8 * lg + i;
        float2 a0 = {W1[e * E_N + lm],        W1[(e + 1) * E_N + lm]};
        float2 a1 = {W1[e * E_N + 16 + lm],   W1[(e + 1) * E_N + 16 + lm]};
        ((__hip_bfloat162*)&w1A)[i >> 1] = __float22bfloat162_rn(a0);
        ((__hip_bfloat162*)&w1B)[i >> 1] = __float22bfloat162_rn(a1);
    }

    const int e0 = 8 * lg;
    const float* rowbase = am + (size_t)b * S_N * E_N + e0;

    float acc[8];
#pragma unroll
    for (int i = 0; i < 8; ++i) acc[i] = 0.0f;

    float amf[8], nxt[8];
    {   // tile 0: rows lm < 16, always valid
        const f32x4* p = (const f32x4*)(rowbase + (size_t)lm * E_N);
        f32x4 v0 = p[0], v1 = p[1];
#pragma unroll
        for (int i = 0; i < 4; ++i) { amf[i] = v0[i]; amf[4 + i] = v1[i]; }
    }

#pragma unroll 2
    for (int t = 0; t < 13; ++t) {
        // ---- prefetch tile t+1 (hides HBM latency under this tile's compute) ----
        if (t < 12) {
            const int r = (t + 1) * 16 + lm;
            if (r < S_N) {
                const f32x4* p = (const f32x4*)(rowbase + (size_t)r * E_N);
                f32x4 v0 = p[0], v1 = p[1];
#pragma unroll
                for (int i = 0; i < 4; ++i) { nxt[i] = v0[i]; nxt[4 + i] = v1[i]; }
            } else {
#pragma unroll
                for (int i = 0; i < 8; ++i) nxt[i] = 0.0f;
            }
        }

        // ---- am rows as MFMA *B* operand: B[k=e][n=r], lane holds col lm, k=8*lg+i ----
        s16x8 af;
#pragma unroll
        for (int i = 0; i < 8; i += 2) {
            float2 a = {amf[i], amf[i + 1]};
            ((__hip_bfloat162*)&af)[i >> 1] = __float22bfloat162_rn(a);
        }

        f32x4 z = {0.0f, 0.0f, 0.0f, 0.0f};
        // D = W1^T * am^T : D[row=f][col=r]  (swapped operands vs am@W1)
        f32x4 d0 = __builtin_amdgcn_mfma_f32_16x16x32_bf16(w1A, af, z, 0, 0, 0);
        f32x4 d1 = __builtin_amdgcn_mfma_f32_16x16x32_bf16(w1B, af, z, 0, 0, 0);

        // partial score for row r=lm: this lane owns 8 of 32 f-terms
        float s = 0.0f;
#pragma unroll
        for (int j = 0; j < 4; ++j) {
            float pA = d0[j] + baseA[j];
            float pB = d1[j] + baseB[j];
            s += w4A[j] * __builtin_amdgcn_rcpf(1.0f + __expf(-pA));
            s += w4B[j] * __builtin_amdgcn_rcpf(1.0f + __expf(-pB));
        }
        // sum the 4 lg-groups (lanes lm, lm+16, lm+32, lm+48): 2 cross-lane ops
        s += __shfl_xor(s, 16);
        s += __shfl_xor(s, 32);
        // every lane now has score for its own loaded row r = t*16+lm

#pragma unroll
        for (int i = 0; i < 8; ++i) acc[i] += s * amf[i];
#pragma unroll
        for (int i = 0; i < 8; ++i) amf[i] = nxt[i];
    }

    // reduce over the 16 row-slots within each e-slice group
#pragma unroll
    for (int i = 0; i < 8; ++i) {
        acc[i] += __shfl_xor(acc[i], 1);
        acc[i] += __shfl_xor(acc[i], 2);
        acc[i] += __shfl_xor(acc[i], 4);
        acc[i] += __shfl_xor(acc[i], 8);
    }
    if (lm == 0) {
        f32x4 o0, o1;
#pragma unroll
        for (int i = 0; i < 4; ++i) { o0[i] = acc[i]; o1[i] = acc[4 + i]; }
        f32x4* po = (f32x4*)(out + (size_t)b * E_N + e0);
        po[0] = o0;
        po[1] = o1;
    }
}

extern "C" void kernel_launch(void* const* d_in, const int* in_sizes, int n_in,
                              void* d_out, int out_size, void* d_ws, size_t ws_size,
                              hipStream_t stream) {
    const float* am    = (const float*)d_in[0];
    const float* lastm = (const float*)d_in[1];
    const float* avgm  = (const float*)d_in[2];
    // d_in[3] = mask: dead code in the reference
    const float* W1 = (const float*)d_in[4];
    const float* b1 = (const float*)d_in[5];
    const float* W2 = (const float*)d_in[6];
    const float* b2 = (const float*)d_in[7];
    const float* W3 = (const float*)d_in[8];
    const float* b3 = (const float*)d_in[9];
    const float* W4 = (const float*)d_in[10];
    float* out = (float*)d_out;

    dim3 grid(B_N / 4);
    dim3 block(256);
    hipLaunchKernelGGL(attn_pool_kernel, grid, block, 0, stream,
                       am, lastm, avgm, W1, b1, W2, b2, W3, b3, W4, out);
}

// Round 3
// 199.339 us; speedup vs baseline: 1.0586x; 1.0586x over previous
//
#include <hip/hip_runtime.h>
#include <hip/hip_bf16.h>

#define B_N 4096
#define S_N 200
#define E_N 32

typedef float f32x4 __attribute__((ext_vector_type(4)));
typedef short s16x8 __attribute__((ext_vector_type(8)));

static __device__ __forceinline__ float sigmoidf_fast(float x) {
    return __builtin_amdgcn_rcpf(1.0f + __expf(-x));
}

__global__ __launch_bounds__(256, 4) void attn_pool_kernel(
    const float* __restrict__ am,    // [B,S,E]
    const float* __restrict__ lastm, // [B,E]
    const float* __restrict__ avgm,  // [B,E]
    const float* __restrict__ W1,    // [E,E]
    const float* __restrict__ b1,    // [E]
    const float* __restrict__ W2,    // [E,E]
    const float* __restrict__ b2,    // [E]
    const float* __restrict__ W3,    // [E,E]
    const float* __restrict__ b3,    // [E]
    const float* __restrict__ W4,    // [E,1]
    float* __restrict__ out)         // [B,E]
{
    const int tid  = threadIdx.x;
    const int l    = tid & 63;
    const int wave = tid >> 6;
    const int b    = blockIdx.x * 4 + wave;

    const int lm = l & 15;   // A-frag row f (mod 16) / am row-slot r
    const int lg = l >> 4;   // k-slice group
    const int fi = l & 31;
    const int e0 = 8 * lg;

    // ---- weight A-fragments: A[m=f][k=e] = W[e*32+f], lane: m=lm(+16), k=e0+i ----
    s16x8 w1A, w1B, w2A, w2B, w3A, w3B;
#pragma unroll
    for (int i = 0; i < 8; i += 2) {
        int e = e0 + i;
        float2 p;
        p = {W1[e * E_N + lm],      W1[(e + 1) * E_N + lm]};
        ((__hip_bfloat162*)&w1A)[i >> 1] = __float22bfloat162_rn(p);
        p = {W1[e * E_N + 16 + lm], W1[(e + 1) * E_N + 16 + lm]};
        ((__hip_bfloat162*)&w1B)[i >> 1] = __float22bfloat162_rn(p);
        p = {W2[e * E_N + lm],      W2[(e + 1) * E_N + lm]};
        ((__hip_bfloat162*)&w2A)[i >> 1] = __float22bfloat162_rn(p);
        p = {W2[e * E_N + 16 + lm], W2[(e + 1) * E_N + 16 + lm]};
        ((__hip_bfloat162*)&w2B)[i >> 1] = __float22bfloat162_rn(p);
        p = {W3[e * E_N + lm],      W3[(e + 1) * E_N + lm]};
        ((__hip_bfloat162*)&w3A)[i >> 1] = __float22bfloat162_rn(p);
        p = {W3[e * E_N + 16 + lm], W3[(e + 1) * E_N + 16 + lm]};
        ((__hip_bfloat162*)&w3B)[i >> 1] = __float22bfloat162_rn(p);
    }

    // ---- last/avg as broadcast-column B-frags: B[k][n] = v[k] for all n ----
    s16x8 lfrag, vfrag;
    {
        const f32x4* pl = (const f32x4*)(lastm + (size_t)b * E_N + e0);
        const f32x4* pa = (const f32x4*)(avgm  + (size_t)b * E_N + e0);
        f32x4 l0 = pl[0], l1 = pl[1];
        f32x4 a0 = pa[0], a1 = pa[1];
#pragma unroll
        for (int i = 0; i < 4; i += 2) {
            ((__hip_bfloat162*)&lfrag)[i >> 1]       = __float22bfloat162_rn({l0[i], l0[i + 1]});
            ((__hip_bfloat162*)&lfrag)[(i + 4) >> 1] = __float22bfloat162_rn({l1[i], l1[i + 1]});
            ((__hip_bfloat162*)&vfrag)[i >> 1]       = __float22bfloat162_rn({a0[i], a0[i + 1]});
            ((__hip_bfloat162*)&vfrag)[(i + 4) >> 1] = __float22bfloat162_rn({a1[i], a1[i + 1]});
        }
    }

    // ---- bias C-input: C[j] at row f=4*lg+j (c0) / 16+4*lg+j (c1), any col ----
    float bsum = b1[fi] + b2[fi] + b3[fi];
    f32x4 c0, c1, w4A, w4B;
#pragma unroll
    for (int j = 0; j < 4; ++j) {
        c0[j]  = __shfl(bsum, 4 * lg + j);
        c1[j]  = __shfl(bsum, 16 + 4 * lg + j);
        w4A[j] = W4[4 * lg + j];
        w4B[j] = W4[16 + 4 * lg + j];
    }
    // fold last@W2 + avg@W3 into the C-inputs (broadcast over all 16 cols)
    c0 = __builtin_amdgcn_mfma_f32_16x16x32_bf16(w2A, lfrag, c0, 0, 0, 0);
    c0 = __builtin_amdgcn_mfma_f32_16x16x32_bf16(w3A, vfrag, c0, 0, 0, 0);
    c1 = __builtin_amdgcn_mfma_f32_16x16x32_bf16(w2B, lfrag, c1, 0, 0, 0);
    c1 = __builtin_amdgcn_mfma_f32_16x16x32_bf16(w3B, vfrag, c1, 0, 0, 0);

    const float* rowbase = am + (size_t)b * S_N * E_N + e0;

    // ---- depth-3 rotating register prefetch, fully unrolled main loop ----
    f32x4 bufs[3][2];
#pragma unroll
    for (int t = 0; t < 3; ++t) {
        const f32x4* p = (const f32x4*)(rowbase + (size_t)(t * 16 + lm) * E_N);
        bufs[t][0] = p[0];
        bufs[t][1] = p[1];
    }

    float acc[8];
#pragma unroll
    for (int i = 0; i < 8; ++i) acc[i] = 0.0f;

#pragma unroll
    for (int t = 0; t < 13; ++t) {
        f32x4 v0 = bufs[t % 3][0];
        f32x4 v1 = bufs[t % 3][1];
        if (t == 12 && lm >= 8) {  // rows 200..207 are out of range
            v0 = f32x4{0.0f, 0.0f, 0.0f, 0.0f};
            v1 = f32x4{0.0f, 0.0f, 0.0f, 0.0f};
        }

        // am rows as B-operand: B[k=e][n=r], lane col=lm, k=e0+i
        s16x8 af;
#pragma unroll
        for (int i = 0; i < 4; i += 2) {
            ((__hip_bfloat162*)&af)[i >> 1]       = __float22bfloat162_rn({v0[i], v0[i + 1]});
            ((__hip_bfloat162*)&af)[(i + 4) >> 1] = __float22bfloat162_rn({v1[i], v1[i + 1]});
        }

        // D[f][r] = (W^T am^T)[f][r] + base[f]
        f32x4 d0 = __builtin_amdgcn_mfma_f32_16x16x32_bf16(w1A, af, c0, 0, 0, 0);
        f32x4 d1 = __builtin_amdgcn_mfma_f32_16x16x32_bf16(w1B, af, c1, 0, 0, 0);

        float s = 0.0f;
#pragma unroll
        for (int j = 0; j < 4; ++j) {
            s += w4A[j] * sigmoidf_fast(d0[j]);
            s += w4B[j] * sigmoidf_fast(d1[j]);
        }
        s += __shfl_xor(s, 16);
        s += __shfl_xor(s, 32);
        // s = score for this lane's own row r = t*16+lm

#pragma unroll
        for (int i = 0; i < 4; ++i) {
            acc[i]     += s * v0[i];
            acc[4 + i] += s * v1[i];
        }

        // refill the slot just consumed with tile t+3
        if (t + 3 < 13) {
            const int r = (t + 3) * 16 + lm;
            if (r < S_N) {
                const f32x4* p = (const f32x4*)(rowbase + (size_t)r * E_N);
                bufs[t % 3][0] = p[0];
                bufs[t % 3][1] = p[1];
            }
            // rows >= S_N: leave stale, masked at consume time (t==12)
        }
    }

    // reduce over the 16 row-slots within each e-slice group
#pragma unroll
    for (int i = 0; i < 8; ++i) {
        acc[i] += __shfl_xor(acc[i], 1);
        acc[i] += __shfl_xor(acc[i], 2);
        acc[i] += __shfl_xor(acc[i], 4);
        acc[i] += __shfl_xor(acc[i], 8);
    }
    if (lm == 0) {
        f32x4 o0, o1;
#pragma unroll
        for (int i = 0; i < 4; ++i) { o0[i] = acc[i]; o1[i] = acc[4 + i]; }
        f32x4* po = (f32x4*)(out + (size_t)b * E_N + e0);
        po[0] = o0;
        po[1] = o1;
    }
}

extern "C" void kernel_launch(void* const* d_in, const int* in_sizes, int n_in,
                              void* d_out, int out_size, void* d_ws, size_t ws_size,
                              hipStream_t stream) {
    const float* am    = (const float*)d_in[0];
    const float* lastm = (const float*)d_in[1];
    const float* avgm  = (const float*)d_in[2];
    // d_in[3] = mask: dead code in the reference
    const float* W1 = (const float*)d_in[4];
    const float* b1 = (const float*)d_in[5];
    const float* W2 = (const float*)d_in[6];
    const float* b2 = (const float*)d_in[7];
    const float* W3 = (const float*)d_in[8];
    const float* b3 = (const float*)d_in[9];
    const float* W4 = (const float*)d_in[10];
    float* out = (float*)d_out;

    dim3 grid(B_N / 4);
    dim3 block(256);
    hipLaunchKernelGGL(attn_pool_kernel, grid, block, 0, stream,
                       am, lastm, avgm, W1, b1, W2, b2, W3, b3, W4, out);
}